// Round 17
// baseline (98.731 us; speedup 1.0000x reference)
//
#include <hip/hip_runtime.h>
#include <hip/hip_bf16.h>
#include <math.h>

// Q=4096, N=50000, D=5, L=2
// GEMM1 (16x16x32, split-bf16 K-packing, A=refs, B=queries):
//   t[ref][q] tile; C/D: col=lane&15=q, row=4*quad+reg=ref
// s = 2^t -> bf16 (round-half-up, v_perm pack) -> fed DIRECTLY as B-frag of
// GEMM2 (16x16x16, n=lane&15=q, k=4*quad+i=ref). GEMM2 A rows:
// {l0_hi, l0_lo, l1_hi, l1_lo, 1, 0...} -> C2 accumulates {o0h,o0l,o1h,o1l,sum}.
// R17 = R15 + padded tile space (3200 tiles = 50/phase exactly): compile-time
// trip count, #pragma unroll 4, no guards/tail divergence. Padded refs have
// b6=-1e30 -> t=-1e30 -> exp2=0.0 exactly -> zero contribution.
#define QTOT   4096
#define NTOT   50000
#define NTILEP 3200            // padded tiles; 3200/64 = 50 per phase
#define NROWS  (NTILEP * 16)   // 51200 ref rows incl. padding
#define NS     64              // n-phases; wave phase = nb*4 + waveid
#define NB     16
#define QG     64
#define MAINBLOCKS (QG * NB)   // 1024 blocks = 4096 waves = 16 waves/CU
#define TPP    50              // tiles per phase (compile-time)
#define ASTEP_IT  (512u * NS)  // ref-table stride per iter
#define LTSTEP_IT (160u * NS)  // loc-table stride per iter
#define PREPN  (NTILEP * 20)   // 64000 compact loc-table entries (covers NROWS too)

// ws layout (bytes); total ~3.08 MB
#define BOFF   0u                          // ref table: [tile][hi16x16B][lo16x16B]
#define BSIZE  ((unsigned)NTILEP * 512u)   // 1,638,400
#define AOFF   (BOFF + BSIZE)              // query table: [q][hi16B][lo16B]
#define ASIZE  (4096u * 32u)               // 131,072
#define ZOFF   (AOFF + ASIZE)              // 256 B zero block
#define LTOFF  (ZOFF + 256u)               // loc table: [tile][20 entries][8B]
#define LTSIZE ((unsigned)NTILEP * 160u)   // 512,000
#define PARTOFF (LTOFF + LTSIZE)           // part: [NB][3][4096] f32

typedef unsigned short ushort_t;
typedef short  s16x8 __attribute__((ext_vector_type(8)));
typedef short  s16x4 __attribute__((ext_vector_type(4)));
typedef float  f32x4 __attribute__((ext_vector_type(4)));

#if __has_builtin(__builtin_amdgcn_exp2f)
#define EXP2F(x) __builtin_amdgcn_exp2f(x)
#else
#define EXP2F(x) exp2f(x)
#endif

#if __has_builtin(__builtin_amdgcn_mfma_f32_16x16x16_bf16)
#define MFMA16(a,b,c) __builtin_amdgcn_mfma_f32_16x16x16_bf16(a,b,c,0,0,0)
#else
#define MFMA16(a,b,c) __builtin_amdgcn_mfma_f32_16x16x16bf16_1k(a,b,c,0,0,0)
#endif

static __device__ __forceinline__ void bsplit(float f, ushort_t& h, ushort_t& l) {
    __hip_bfloat16 hb = __float2bfloat16(f);
    float hf = __bfloat162float(hb);
    __hip_bfloat16 lb = __float2bfloat16(f - hf);
    h = *reinterpret_cast<ushort_t*>(&hb);
    l = *reinterpret_cast<ushort_t*>(&lb);
}

static __device__ __forceinline__ ushort_t b16(float f) {
    __hip_bfloat16 hb = __float2bfloat16(f);
    return *reinterpret_cast<ushort_t*>(&hb);
}

__global__ __launch_bounds__(256) void sknn_prep(
    const float* __restrict__ rss, const float* __restrict__ Radio,
    const float* __restrict__ Loc, const float* __restrict__ sigma,
    char* __restrict__ ws)
{
    const int p = blockIdx.x * 256 + threadIdx.x;   // grid covers PREPN=64000
    const float sg = sigma[0];
    const float g  = 1.4426950408889634f / (2.0f * sg * sg);
    const float g2 = 2.0f * g;

    if (p < NROWS) {   // ref entry; padded rows (p>=NTOT): b6=-1e30 -> s==0
        float b[8] = {0.f, 0.f, 0.f, 0.f, 0.f, 1.0f, -1e30f, 0.f};
        if (p < NTOT) {
            float rr = 0.f;
            #pragma unroll
            for (int d = 0; d < 5; ++d) { float r = Radio[p*5+d]; b[d] = g2*r; rr += r*r; }
            b[6] = -g * rr;
        }
        union { ushort_t u[8]; f32x4 v; } hi, lo;
        #pragma unroll
        for (int k = 0; k < 8; ++k) bsplit(b[k], hi.u[k], lo.u[k]);
        const int nt = p >> 4, nsub = p & 15;
        *(f32x4*)(ws + BOFF + (unsigned)nt*512u + (unsigned)nsub*16u)        = hi.v;
        *(f32x4*)(ws + BOFF + (unsigned)nt*512u + 256u + (unsigned)nsub*16u) = lo.v;
    }
    if (p < QTOT) {    // query entry: {x, -g|x|^2, 1, 0} split-bf16
        float a[8]; float xx = 0.f;
        #pragma unroll
        for (int d = 0; d < 5; ++d) { float x = rss[p*5+d]; a[d] = x; xx += x*x; }
        a[5] = -g * xx; a[6] = 1.0f; a[7] = 0.0f;
        union { ushort_t u[8]; f32x4 v; } hi, lo;
        #pragma unroll
        for (int k = 0; k < 8; ++k) bsplit(a[k], hi.u[k], lo.u[k]);
        *(f32x4*)(ws + AOFF + (unsigned)p*32u)       = hi.v;
        *(f32x4*)(ws + AOFF + (unsigned)p*32u + 16u) = lo.v;
    }
    if (p < PREPN) {   // loc table: tile T, compact entry c = m*4+quad (m<5)
        const int T = p / 20;
        const int c = p - T * 20;
        const int m = c >> 2, qq = c & 3;
        union { ushort_t u[4]; s16x4 v; } e;
        #pragma unroll
        for (int i = 0; i < 4; ++i) {
            const int n = T*16 + qq*4 + i;
            ushort_t val;
            if (m == 4) { val = b16(1.0f); }
            else if (n < NTOT) {
                ushort_t h, l;
                bsplit(Loc[n*2 + (m >> 1)], h, l);
                val = (m & 1) ? l : h;
            } else val = 0;      // padded tile: s==0 anyway
            e.u[i] = val;
        }
        *(s16x4*)(ws + LTOFF + (unsigned)T*160u + (unsigned)c*8u) = e.v;
    }
    if (p < 16) *(f32x4*)(ws + ZOFF + (unsigned)p*16u) = (f32x4){0.f,0.f,0.f,0.f};
}

// exp + bf16 round-half-up pack (v_perm packs 2) + accumulate-MFMA
static __device__ __forceinline__ f32x4 step2(
    const f32x4 t, const s16x4 lt, f32x4 c)
{
    union { unsigned u[4]; float f[4]; } s;
    s.f[0] = EXP2F(t[0]);
    s.f[1] = EXP2F(t[1]);
    s.f[2] = EXP2F(t[2]);
    s.f[3] = EXP2F(t[3]);
    const unsigned w0 = __builtin_amdgcn_perm(s.u[1] + 0x8000u, s.u[0] + 0x8000u, 0x07060302u);
    const unsigned w1 = __builtin_amdgcn_perm(s.u[3] + 0x8000u, s.u[2] + 0x8000u, 0x07060302u);
    union { unsigned w[2]; s16x4 v; } bs;
    bs.w[0] = w0; bs.w[1] = w1;
    return MFMA16(lt, bs.v, c);
}

static __device__ __forceinline__ void tile_step(
    const s16x8 a, const s16x4 lt,
    const s16x8 bq0, const s16x8 bq1, const s16x8 bq2, const s16x8 bq3,
    f32x4* c2)
{
    const f32x4 zz = {0.f, 0.f, 0.f, 0.f};
    const f32x4 t0 = __builtin_amdgcn_mfma_f32_16x16x32_bf16(a, bq0, zz, 0, 0, 0);
    const f32x4 t1 = __builtin_amdgcn_mfma_f32_16x16x32_bf16(a, bq1, zz, 0, 0, 0);
    const f32x4 t2 = __builtin_amdgcn_mfma_f32_16x16x32_bf16(a, bq2, zz, 0, 0, 0);
    const f32x4 t3 = __builtin_amdgcn_mfma_f32_16x16x32_bf16(a, bq3, zz, 0, 0, 0);
    c2[0] = step2(t0, lt, c2[0]);
    c2[1] = step2(t1, lt, c2[1]);
    c2[2] = step2(t2, lt, c2[2]);
    c2[3] = step2(t3, lt, c2[3]);
}

__global__ __launch_bounds__(256, 4) void sknn_main(
    const char* __restrict__ tbl, float* __restrict__ part)
{
    const int tid  = threadIdx.x;
    const int lane = tid & 63;
    const int w    = tid >> 6;
    const int nb   = blockIdx.x & (NB - 1);           // XCD swizzle
    const int qg   = blockIdx.x >> 4;
    const int ns   = nb * 4 + w;                      // phase 0..63
    const int qbase = qg * 64;
    const int j  = lane & 15;
    const int qd = lane >> 4;

    // GEMM1 B-frags = queries, K-pattern [Qh|Ql|Qh|0] (quad1 -> lo half)
    const unsigned qb = (qd == 3) ? (ZOFF + (unsigned)j*16u)
        : (AOFF + (unsigned)(qbase + j)*32u + (qd == 1 ? 16u : 0u));
    const unsigned qs = (qd == 3) ? 0u : 512u;        // 16 queries * 32 B
    const s16x8 bq0 = *(const s16x8*)(tbl + qb);
    const s16x8 bq1 = *(const s16x8*)(tbl + qb + qs);
    const s16x8 bq2 = *(const s16x8*)(tbl + qb + 2u*qs);
    const s16x8 bq3 = *(const s16x8*)(tbl + qb + 3u*qs);

    // GEMM1 A-stream = refs, K-pattern [Rh|Rh|Rl|0] (quad2 -> lo half)
    const unsigned aofs = (qd == 3) ? (ZOFF + (unsigned)j*16u)
        : (BOFF + (unsigned)ns*512u + (qd == 2 ? 256u : 0u) + (unsigned)j*16u);
    const unsigned astep = (qd == 3) ? 0u : ASTEP_IT;

    // GEMM2 A-stream = loc weights; lane m=j, k=4*qd+i. m>=5 rows are zero.
    const unsigned ltofs = (j < 5) ? (LTOFF + (unsigned)ns*160u + (unsigned)(j*4+qd)*8u)
                                   : ZOFF;
    const unsigned ltstep = (j < 5) ? LTSTEP_IT : 0u;

    f32x4 c2[4];
    #pragma unroll
    for (int k = 0; k < 4; ++k) c2[k] = (f32x4){0.f, 0.f, 0.f, 0.f};

    // depth-2 pipeline over a COMPILE-TIME 50-tile phase: 48 hot + 2 tail
    s16x8 a0v = *(const s16x8*)(tbl + aofs);
    s16x4 l0v = *(const s16x4*)(tbl + ltofs);
    s16x8 a1v = *(const s16x8*)(tbl + aofs + astep);
    s16x4 l1v = *(const s16x4*)(tbl + ltofs + ltstep);
    unsigned apf = aofs + 2u*astep, lpf = ltofs + 2u*ltstep;

    #pragma unroll 4
    for (int it = 0; it < TPP - 2; ++it) {   // 48 iterations, 48 % 4 == 0
        const s16x8 anx = *(const s16x8*)(tbl + apf);
        const s16x4 lnx = *(const s16x4*)(tbl + lpf);
        apf += astep; lpf += ltstep;

        tile_step(a0v, l0v, bq0, bq1, bq2, bq3, c2);

        a0v = a1v; l0v = l1v;        // renamed away under unroll
        a1v = anx; l1v = lnx;
    }
    tile_step(a0v, l0v, bq0, bq1, bq2, bq3, c2);   // tail tiles 48, 49
    tile_step(a1v, l1v, bq0, bq1, bq2, bq3, c2);

    // C2 rows (m = 4*qd + reg): qd0 -> {o0h,o0l,o1h,o1l}; qd1 reg0 -> sum.
    // Fully reduced over this wave's n-subset — no butterfly needed.
    __shared__ float red[4][3][64];
    if (qd == 0) {
        #pragma unroll
        for (int qt = 0; qt < 4; ++qt) {
            red[w][1][qt*16 + j] = c2[qt][0] + c2[qt][1];
            red[w][2][qt*16 + j] = c2[qt][2] + c2[qt][3];
        }
    } else if (qd == 1) {
        #pragma unroll
        for (int qt = 0; qt < 4; ++qt) {
            red[w][0][qt*16 + j] = c2[qt][0];
        }
    }
    __syncthreads();

    if (tid < 192) {   // sum 4 waves, coalesced store (no atomics)
        const int comp = tid >> 6, ql = tid & 63;
        const float v = red[0][comp][ql] + red[1][comp][ql]
                      + red[2][comp][ql] + red[3][comp][ql];
        part[((nb * 3 + comp) << 12) + qbase + ql] = v;
    }
}

__global__ __launch_bounds__(256) void sknn_fin(
    const float* __restrict__ part, float* __restrict__ out)
{
    const int q = blockIdx.x * 256 + threadIdx.x;
    float s = 0.f, w0 = 0.f, w1 = 0.f;
    #pragma unroll
    for (int nb = 0; nb < NB; ++nb) {
        s  += part[((nb * 3 + 0) << 12) + q];
        w0 += part[((nb * 3 + 1) << 12) + q];
        w1 += part[((nb * 3 + 2) << 12) + q];
    }
    const float inv = 1.0f / s;
    out[q * 2 + 0] = w0 * inv;
    out[q * 2 + 1] = w1 * inv;
}

extern "C" void kernel_launch(void* const* d_in, const int* in_sizes, int n_in,
                              void* d_out, int out_size, void* d_ws, size_t ws_size,
                              hipStream_t stream) {
    const float* rss   = (const float*)d_in[0];
    const float* Radio = (const float*)d_in[1];
    const float* Loc   = (const float*)d_in[2];
    const float* sigma = (const float*)d_in[3];
    float* out  = (float*)d_out;
    char*  ws   = (char*)d_ws;
    float* part = (float*)(ws + PARTOFF);

    sknn_prep<<<(PREPN + 255) / 256, dim3(256), 0, stream>>>(rss, Radio, Loc, sigma, ws);
    sknn_main<<<MAINBLOCKS, dim3(256), 0, stream>>>(ws, part);
    sknn_fin<<<QTOT / 256, dim3(256), 0, stream>>>(part, out);
}

// Round 18
// 96.410 us; speedup vs baseline: 1.0241x; 1.0241x over previous
//
#include <hip/hip_runtime.h>
#include <hip/hip_bf16.h>
#include <math.h>

// Q=4096, N=50000, D=5, L=2
// GEMM1 (16x16x32, split-bf16 K-packing, A=refs, B=queries):
//   t[ref][q] tile; C/D: col=lane&15=q, row=4*quad+reg=ref
// s = 2^t -> bf16 (round-half-up via +0x8000, packed by v_perm) -> fed
// DIRECTLY as B-frag of GEMM2 (16x16x16, n=lane&15=q, k=4*quad+i=ref).
// GEMM2 A rows: {l0_hi, l0_lo, l1_hi, l1_lo, 1, 0...} (split-bf16 Loc) ->
// C2 rows accumulate {o0h,o0l,o1h,o1l,sum} over the sweep in AGPRs.
// R18 = R15 verbatim (best measured total: 95.8 µs, absmax 4.88e-4).
#define QTOT   4096
#define NTOT   50000
#define NTILES 3125            // 50000/16 exactly
#define NS     64              // n-phases; wave phase = nb*4 + waveid
#define NB     16
#define QG     64
#define MAINBLOCKS (QG * NB)   // 1024 blocks = 4096 waves
#define ASTEP_IT  (512u * NS)  // ref-table stride per iter
#define LTSTEP_IT (160u * NS)  // loc-table stride per iter
#define PREPN  (NTILES * 20)   // 62500 compact loc-table entries

// ws layout (bytes); total ~3.02 MB
#define BOFF   0u                          // ref table: [tile][hi16x16B][lo16x16B]
#define BSIZE  (3125u * 512u)              // 1,600,000
#define AOFF   (BOFF + BSIZE)              // query table: [q][hi16B][lo16B]
#define ASIZE  (4096u * 32u)               // 131,072
#define ZOFF   (AOFF + ASIZE)              // 256 B zero block
#define LTOFF  (ZOFF + 256u)               // loc table: [tile][20 entries][8B]
#define LTSIZE (3125u * 160u)              // 500,000
#define PARTOFF (LTOFF + LTSIZE)           // part: [NB][3][4096] f32

typedef unsigned short ushort_t;
typedef short  s16x8 __attribute__((ext_vector_type(8)));
typedef short  s16x4 __attribute__((ext_vector_type(4)));
typedef float  f32x4 __attribute__((ext_vector_type(4)));

#if __has_builtin(__builtin_amdgcn_exp2f)
#define EXP2F(x) __builtin_amdgcn_exp2f(x)
#else
#define EXP2F(x) exp2f(x)
#endif

#if __has_builtin(__builtin_amdgcn_mfma_f32_16x16x16_bf16)
#define MFMA16(a,b,c) __builtin_amdgcn_mfma_f32_16x16x16_bf16(a,b,c,0,0,0)
#else
#define MFMA16(a,b,c) __builtin_amdgcn_mfma_f32_16x16x16bf16_1k(a,b,c,0,0,0)
#endif

static __device__ __forceinline__ void bsplit(float f, ushort_t& h, ushort_t& l) {
    __hip_bfloat16 hb = __float2bfloat16(f);
    float hf = __bfloat162float(hb);
    __hip_bfloat16 lb = __float2bfloat16(f - hf);
    h = *reinterpret_cast<ushort_t*>(&hb);
    l = *reinterpret_cast<ushort_t*>(&lb);
}

static __device__ __forceinline__ ushort_t b16(float f) {
    __hip_bfloat16 hb = __float2bfloat16(f);
    return *reinterpret_cast<ushort_t*>(&hb);
}

__global__ __launch_bounds__(256) void sknn_prep(
    const float* __restrict__ rss, const float* __restrict__ Radio,
    const float* __restrict__ Loc, const float* __restrict__ sigma,
    char* __restrict__ ws)
{
    const int p = blockIdx.x * 256 + threadIdx.x;   // grid covers PREPN
    const float sg = sigma[0];
    const float g  = 1.4426950408889634f / (2.0f * sg * sg);
    const float g2 = 2.0f * g;

    if (p < NTOT) {    // ref entry: {2g*r, 1, -g|r|^2, 0} split-bf16
        float b[8]; float rr = 0.f;
        #pragma unroll
        for (int d = 0; d < 5; ++d) { float r = Radio[p*5+d]; b[d] = g2*r; rr += r*r; }
        b[5] = 1.0f; b[6] = -g * rr; b[7] = 0.0f;
        union { ushort_t u[8]; f32x4 v; } hi, lo;
        #pragma unroll
        for (int k = 0; k < 8; ++k) bsplit(b[k], hi.u[k], lo.u[k]);
        const int nt = p >> 4, nsub = p & 15;
        *(f32x4*)(ws + BOFF + (unsigned)nt*512u + (unsigned)nsub*16u)        = hi.v;
        *(f32x4*)(ws + BOFF + (unsigned)nt*512u + 256u + (unsigned)nsub*16u) = lo.v;
    }
    if (p < QTOT) {    // query entry: {x, -g|x|^2, 1, 0} split-bf16
        float a[8]; float xx = 0.f;
        #pragma unroll
        for (int d = 0; d < 5; ++d) { float x = rss[p*5+d]; a[d] = x; xx += x*x; }
        a[5] = -g * xx; a[6] = 1.0f; a[7] = 0.0f;
        union { ushort_t u[8]; f32x4 v; } hi, lo;
        #pragma unroll
        for (int k = 0; k < 8; ++k) bsplit(a[k], hi.u[k], lo.u[k]);
        *(f32x4*)(ws + AOFF + (unsigned)p*32u)       = hi.v;
        *(f32x4*)(ws + AOFF + (unsigned)p*32u + 16u) = lo.v;
    }
    if (p < PREPN) {   // loc table: tile T, compact entry c = m*4+quad (m<5)
        const int T = p / 20;
        const int c = p - T * 20;
        const int m = c >> 2, qq = c & 3;
        union { ushort_t u[4]; s16x4 v; } e;
        #pragma unroll
        for (int i = 0; i < 4; ++i) {
            const int n = T*16 + qq*4 + i;
            ushort_t h, l, val;
            if (m == 0)      { bsplit(Loc[n*2+0], h, l); val = h; }
            else if (m == 1) { bsplit(Loc[n*2+0], h, l); val = l; }
            else if (m == 2) { bsplit(Loc[n*2+1], h, l); val = h; }
            else if (m == 3) { bsplit(Loc[n*2+1], h, l); val = l; }
            else             { val = b16(1.0f); }
            e.u[i] = val;
        }
        *(s16x4*)(ws + LTOFF + (unsigned)T*160u + (unsigned)c*8u) = e.v;
    }
    if (p < 16) *(f32x4*)(ws + ZOFF + (unsigned)p*16u) = (f32x4){0.f,0.f,0.f,0.f};
}

// exp + bf16 round-half-up pack (v_perm: 1 instr packs 2) + accumulate-MFMA
static __device__ __forceinline__ f32x4 step2(
    const f32x4 t, const s16x4 lt, f32x4 c)
{
    union { unsigned u[4]; float f[4]; } s;
    s.f[0] = EXP2F(t[0]);
    s.f[1] = EXP2F(t[1]);
    s.f[2] = EXP2F(t[2]);
    s.f[3] = EXP2F(t[3]);
    // round-half-up to bf16: +0x8000 then take high 16 bits; s>=0 finite.
    const unsigned w0 = __builtin_amdgcn_perm(s.u[1] + 0x8000u, s.u[0] + 0x8000u, 0x07060302u);
    const unsigned w1 = __builtin_amdgcn_perm(s.u[3] + 0x8000u, s.u[2] + 0x8000u, 0x07060302u);
    union { unsigned w[2]; s16x4 v; } bs;
    bs.w[0] = w0; bs.w[1] = w1;
    return MFMA16(lt, bs.v, c);
}

static __device__ __forceinline__ void tile_step(
    const s16x8 a, const s16x4 lt,
    const s16x8 bq0, const s16x8 bq1, const s16x8 bq2, const s16x8 bq3,
    f32x4* c2)
{
    const f32x4 zz = {0.f, 0.f, 0.f, 0.f};
    const f32x4 t0 = __builtin_amdgcn_mfma_f32_16x16x32_bf16(a, bq0, zz, 0, 0, 0);
    const f32x4 t1 = __builtin_amdgcn_mfma_f32_16x16x32_bf16(a, bq1, zz, 0, 0, 0);
    const f32x4 t2 = __builtin_amdgcn_mfma_f32_16x16x32_bf16(a, bq2, zz, 0, 0, 0);
    const f32x4 t3 = __builtin_amdgcn_mfma_f32_16x16x32_bf16(a, bq3, zz, 0, 0, 0);
    c2[0] = step2(t0, lt, c2[0]);
    c2[1] = step2(t1, lt, c2[1]);
    c2[2] = step2(t2, lt, c2[2]);
    c2[3] = step2(t3, lt, c2[3]);
}

__global__ __launch_bounds__(256, 4) void sknn_main(
    const char* __restrict__ tbl, float* __restrict__ part)
{
    const int tid  = threadIdx.x;
    const int lane = tid & 63;
    const int w    = tid >> 6;
    const int nb   = blockIdx.x & (NB - 1);           // XCD swizzle
    const int qg   = blockIdx.x >> 4;
    const int ns   = nb * 4 + w;                      // phase 0..63
    const int qbase = qg * 64;
    const int j  = lane & 15;
    const int qd = lane >> 4;

    // GEMM1 B-frags = queries, K-pattern [Qh|Ql|Qh|0] (quad1 -> lo half)
    const unsigned qb = (qd == 3) ? (ZOFF + (unsigned)j*16u)
        : (AOFF + (unsigned)(qbase + j)*32u + (qd == 1 ? 16u : 0u));
    const unsigned qs = (qd == 3) ? 0u : 512u;        // 16 queries * 32 B
    const s16x8 bq0 = *(const s16x8*)(tbl + qb);
    const s16x8 bq1 = *(const s16x8*)(tbl + qb + qs);
    const s16x8 bq2 = *(const s16x8*)(tbl + qb + 2u*qs);
    const s16x8 bq3 = *(const s16x8*)(tbl + qb + 3u*qs);

    // GEMM1 A-stream = refs, K-pattern [Rh|Rh|Rl|0] (quad2 -> lo half)
    unsigned aofs = (qd == 3) ? (ZOFF + (unsigned)j*16u)
        : (BOFF + (unsigned)ns*512u + (qd == 2 ? 256u : 0u) + (unsigned)j*16u);
    const unsigned astep = (qd == 3) ? 0u : ASTEP_IT;

    // GEMM2 A-stream = loc weights; lane m=j, k=4*qd+i. m>=5 rows are zero.
    unsigned ltofs = (j < 5) ? (LTOFF + (unsigned)ns*160u + (unsigned)(j*4+qd)*8u)
                             : ZOFF;
    const unsigned ltstep = (j < 5) ? LTSTEP_IT : 0u;

    f32x4 c2[4];
    #pragma unroll
    for (int k = 0; k < 4; ++k) c2[k] = (f32x4){0.f, 0.f, 0.f, 0.f};

    // depth-2 software pipeline (every wave has >= 48 iterations)
    s16x8 a0v = *(const s16x8*)(tbl + aofs);
    s16x4 l0v = *(const s16x4*)(tbl + ltofs);
    unsigned aofs1 = aofs + astep, ltofs1 = ltofs + ltstep;
    s16x8 a1v = *(const s16x8*)(tbl + aofs1);
    s16x4 l1v = *(const s16x4*)(tbl + ltofs1);

    int nt = ns;
    while (nt + 2*NS < NTILES) {     // hot loop: prefetch 2 tiles ahead
        aofs1  += astep;
        ltofs1 += ltstep;
        const s16x8 anx = *(const s16x8*)(tbl + aofs1);
        const s16x4 lnx = *(const s16x4*)(tbl + ltofs1);

        tile_step(a0v, l0v, bq0, bq1, bq2, bq3, c2);

        a0v = a1v; l0v = l1v;
        a1v = anx; l1v = lnx;
        nt += NS;
    }
    tile_step(a0v, l0v, bq0, bq1, bq2, bq3, c2);  // 2 peeled tail iters
    tile_step(a1v, l1v, bq0, bq1, bq2, bq3, c2);

    // C2 rows (m = 4*qd + reg): qd0 -> {o0h,o0l,o1h,o1l}; qd1 reg0 -> sum.
    // Fully reduced over this wave's n-subset — no butterfly needed.
    __shared__ float red[4][3][64];
    if (qd == 0) {
        #pragma unroll
        for (int qt = 0; qt < 4; ++qt) {
            red[w][1][qt*16 + j] = c2[qt][0] + c2[qt][1];
            red[w][2][qt*16 + j] = c2[qt][2] + c2[qt][3];
        }
    } else if (qd == 1) {
        #pragma unroll
        for (int qt = 0; qt < 4; ++qt) {
            red[w][0][qt*16 + j] = c2[qt][0];
        }
    }
    __syncthreads();

    if (tid < 192) {   // sum 4 waves, coalesced store (no atomics)
        const int comp = tid >> 6, ql = tid & 63;
        const float v = red[0][comp][ql] + red[1][comp][ql]
                      + red[2][comp][ql] + red[3][comp][ql];
        part[((nb * 3 + comp) << 12) + qbase + ql] = v;
    }
}

__global__ __launch_bounds__(256) void sknn_fin(
    const float* __restrict__ part, float* __restrict__ out)
{
    const int q = blockIdx.x * 256 + threadIdx.x;
    float s = 0.f, w0 = 0.f, w1 = 0.f;
    #pragma unroll
    for (int nb = 0; nb < NB; ++nb) {
        s  += part[((nb * 3 + 0) << 12) + q];
        w0 += part[((nb * 3 + 1) << 12) + q];
        w1 += part[((nb * 3 + 2) << 12) + q];
    }
    const float inv = 1.0f / s;
    out[q * 2 + 0] = w0 * inv;
    out[q * 2 + 1] = w1 * inv;
}

extern "C" void kernel_launch(void* const* d_in, const int* in_sizes, int n_in,
                              void* d_out, int out_size, void* d_ws, size_t ws_size,
                              hipStream_t stream) {
    const float* rss   = (const float*)d_in[0];
    const float* Radio = (const float*)d_in[1];
    const float* Loc   = (const float*)d_in[2];
    const float* sigma = (const float*)d_in[3];
    float* out  = (float*)d_out;
    char*  ws   = (char*)d_ws;
    float* part = (float*)(ws + PARTOFF);

    sknn_prep<<<(PREPN + 255) / 256, dim3(256), 0, stream>>>(rss, Radio, Loc, sigma, ws);
    sknn_main<<<MAINBLOCKS, dim3(256), 0, stream>>>(ws, part);
    sknn_fin<<<QTOT / 256, dim3(256), 0, stream>>>(part, out);
}